// Round 4
// baseline (289.843 us; speedup 1.0000x reference)
//
#include <hip/hip_runtime.h>
#include <hip/hip_bf16.h>

typedef __attribute__((ext_vector_type(8))) __bf16 bf16x8;
typedef __attribute__((ext_vector_type(4))) float f32x4;

#define GLOBAL_CPTR(x) ((__attribute__((address_space(1))) const void*)(x))
#define LDS_PTR(x)     ((__attribute__((address_space(3))) void*)(x))

// ---------------------------------------------------------------------------
// MXFP4 fake-quantize: fp32 -> bf16 (exact representation of dequant values)
// ---------------------------------------------------------------------------
__global__ __launch_bounds__(256) void mxfp4_quant_kernel(
    const float* __restrict__ in, ushort* __restrict__ out, long long n) {
  long long base = ((long long)blockIdx.x * 256 + threadIdx.x) * 4;
  if (base >= n) return;

  float4 v = *reinterpret_cast<const float4*>(in + base);
  float am = fmaxf(fmaxf(fabsf(v.x), fabsf(v.y)), fmaxf(fabsf(v.z), fabsf(v.w)));
  am = fmaxf(am, __shfl_xor(am, 1, 64));
  am = fmaxf(am, __shfl_xor(am, 2, 64));
  am = fmaxf(am, __shfl_xor(am, 4, 64));

  float safe = am > 0.f ? am : 1.f;
  int se = ilogbf(safe) - 2;           // floor(log2(amax)) - E2M1_EMAX
  float scale = ldexpf(1.f, se);
  float inv   = ldexpf(1.f, -se);

  float vv[4] = {v.x, v.y, v.z, v.w};
  ushort o16[4];
#pragma unroll
  for (int j = 0; j < 4; ++j) {
    float val = vv[j] * inv;                 // exact (power-of-2)
    float av = fabsf(val);
    float avc = fmaxf(av, 9.765625e-4f);     // 2^-10 floor
    int e = (int)((__float_as_uint(avc) >> 23) & 0xFF) - 127;  // floor(log2)
    e = e < 0 ? 0 : (e > 2 ? 2 : e);
    float step  = ldexpf(1.f, e - 1);
    float istep = ldexpf(1.f, 1 - e);
    float q = rintf(av * istep) * step;      // round-half-to-even
    q = fminf(q, 6.f);
    float r = copysignf(q * scale, val);     // exact in bf16
    __hip_bfloat16 b = __float2bfloat16(r);
    o16[j] = *reinterpret_cast<ushort*>(&b);
  }
  ushort4 packed = make_ushort4(o16[0], o16[1], o16[2], o16[3]);
  *reinterpret_cast<ushort4*>(out + base) = packed;
}

// ---------------------------------------------------------------------------
// 256x256 bf16 GEMM, 2 phases per K-tile, ONE barrier per phase.
// C[M][N] = A[M][K]*B[N][K]^T + bias[N]
// 8 waves (2Mx4N), BK=64, 128KiB LDS dbuf, st_16x32 swizzle.
// Phase = K-half: read 12 frags, 32 MFMA (setprio), 4 staging gloads,
// counted vmcnt (4/2/4/2 ledger, never 0), s_barrier.
// LDS layout (ushort): [buf:32768][op A=0/B=16384][half(128r):8192]
//                      [rowblock(16r):1024][khalf:512][row:32][kcol]
// Stage unit = {half H, rowblock wid, khalf KH}: wave w stages rowblock w of
// both halves, both K-halves (symmetric per-wave vmcnt accounting).
// ---------------------------------------------------------------------------
#define BM 256
#define BN 256
#define NTHR 512

__global__ __launch_bounds__(NTHR, 2) void mxfp_gemm_kernel(
    const ushort* __restrict__ A, const ushort* __restrict__ B,
    const float* __restrict__ bias, float* __restrict__ C,
    int M, int N, int K) {
  __shared__ ushort lds[65536];  // 128 KiB

  const int tid = threadIdx.x;
  const int l   = tid & 63;
  const int wid = tid >> 6;
  const int wm  = wid >> 2;  // 0..1
  const int wn  = wid & 3;   // 0..3

  const int nwg = gridDim.x;       // multiple of 8
  const int bid = blockIdx.x;
  const int swz = (bid & 7) * (nwg >> 3) + (bid >> 3);
  const int nbn = N / BN;
  const int bm  = swz / nbn;
  const int bn  = swz % nbn;

  // swizzled per-lane ds_read offset (ushorts)
  const int laneRd = ((l & 15) << 5) + (((l >> 4) << 3) ^ ((l & 8) ? 16 : 0));
  const int aRd = (wm << 13) + laneRd;
  const int bRd = 16384 + ((wn >> 1) << 13) + ((wn & 1) << 12) + laneRd;

  // staging: per-lane inverse-swizzled global source; linear LDS dest.
  // lane l covers row (l>>2) of the unit, 16B at kcol (l&3)*8 (^swz on row&8).
  const int colSwz = ((l & 3) << 3) ^ ((l & 32) ? 16 : 0);
  const ushort* aUnit = A + (size_t)(bm * BM + wid * 16 + (l >> 2)) * K + colSwz;
  const ushort* bUnit = B + (size_t)(bn * BN + wid * 16 + (l >> 2)) * K + colSwz;

  f32x4 acc[8][4] = {};

// stage one op's {H0,H1} pair for K-half KH of K-tile at KT into buffer BUFO
#define STG2(UNIT, BUFO, OPO, KH, KT)                                           \
  do {                                                                          \
    __builtin_amdgcn_global_load_lds(                                           \
        GLOBAL_CPTR((UNIT) + (KT) + (KH) * 32),                                 \
        LDS_PTR(lds + (BUFO) + (OPO) + (wid << 10) + ((KH) << 9)), 16, 0, 0);   \
    __builtin_amdgcn_global_load_lds(                                           \
        GLOBAL_CPTR((UNIT) + (size_t)128 * K + (KT) + (KH) * 32),               \
        LDS_PTR(lds + (BUFO) + (OPO) + 8192 + (wid << 10) + ((KH) << 9)),       \
        16, 0, 0);                                                              \
  } while (0)

// one phase: K-half KH of the tile in BUFO; STGS = 4 staging gloads;
// VMN = counted vmcnt before the single phase-end barrier.
#define PHASE(BUFO, KH, STGS, VMN)                                              \
  do {                                                                          \
    bf16x8 bfr[4], af[8];                                                       \
    _Pragma("unroll") for (int nb = 0; nb < 4; ++nb)                            \
      bfr[nb] = *(const bf16x8*)(lds + (BUFO) + bRd + (nb << 10) + ((KH) << 9));\
    _Pragma("unroll") for (int mb = 0; mb < 8; ++mb)                            \
      af[mb] = *(const bf16x8*)(lds + (BUFO) + aRd + (mb << 10) + ((KH) << 9)); \
    STGS;                                                                       \
    __builtin_amdgcn_s_setprio(1);                                              \
    _Pragma("unroll") for (int mb = 0; mb < 8; ++mb)                            \
      _Pragma("unroll") for (int nb = 0; nb < 4; ++nb)                          \
        acc[mb][nb] = __builtin_amdgcn_mfma_f32_16x16x32_bf16(                  \
            af[mb], bfr[nb], acc[mb][nb], 0, 0, 0);                             \
    __builtin_amdgcn_s_setprio(0);                                              \
    asm volatile("s_waitcnt vmcnt(" #VMN ")" ::: "memory");                     \
    __builtin_amdgcn_s_barrier();                                               \
    asm volatile("" ::: "memory");                                              \
  } while (0)

  // prologue: stage tile0 (B then A, kh0-pairs before kh1-pairs) into buf0.
  // vmcnt(2) waits B[0] all + A[0]kh0; A[0]kh1 guarded by P1-end vmcnt(4).
  STG2(bUnit, 0, 16384, 0, 0);
  STG2(bUnit, 0, 16384, 1, 0);
  STG2(aUnit, 0, 0, 0, 0);
  STG2(aUnit, 0, 0, 1, 0);
  asm volatile("s_waitcnt vmcnt(2)" ::: "memory");
  __builtin_amdgcn_s_barrier();
  asm volatile("" ::: "memory");

  const int NKT = K >> 6;  // K-tiles (even)
  for (int it = 0; it < (NKT >> 1); ++it) {
    const int t    = it << 1;
    const int ktn  = (t + 1) << 6;                                // live
    const int ktn2 = ((t + 2 < NKT) ? (t + 2) : (NKT - 1)) << 6;  // clamp->dead
    // P1: tile t kh0 (buf0); stage B[t+1]->buf1.  vmcnt(4): waits A[t]kh1.
    PHASE(0, 0,
          { STG2(bUnit, 32768, 16384, 0, ktn); STG2(bUnit, 32768, 16384, 1, ktn); },
          4);
    // P2: tile t kh1; stage A[t+1]->buf1.  vmcnt(2): waits B[t+1]+A[t+1]kh0.
    PHASE(0, 1,
          { STG2(aUnit, 32768, 0, 0, ktn); STG2(aUnit, 32768, 0, 1, ktn); },
          2);
    // P3: tile t+1 kh0 (buf1); stage B[t+2]->buf0.  vmcnt(4): waits A[t+1]kh1.
    PHASE(32768, 0,
          { STG2(bUnit, 0, 16384, 0, ktn2); STG2(bUnit, 0, 16384, 1, ktn2); },
          4);
    // P4: tile t+1 kh1; stage A[t+2]->buf0.  vmcnt(2): waits B[t+2]+A[t+2]kh0.
    PHASE(32768, 1,
          { STG2(aUnit, 0, 0, 0, ktn2); STG2(aUnit, 0, 0, 1, ktn2); },
          2);
  }
  asm volatile("s_waitcnt vmcnt(0)" ::: "memory");  // drain dead tail stages

  // epilogue: C/D layout col=lane&15, row=(lane>>4)*4+reg (m89-verified)
  const int colb = bn * BN + wn * 64 + (l & 15);
  const long long rowb = (long long)bm * BM + wm * 128 + ((l >> 4) << 2);
#pragma unroll
  for (int j = 0; j < 4; ++j) {
    const float bv = bias[colb + j * 16];
#pragma unroll
    for (int i = 0; i < 8; ++i) {
#pragma unroll
      for (int r = 0; r < 4; ++r) {
        C[(rowb + i * 16 + r) * N + (colb + j * 16)] = acc[i][j][r] + bv;
      }
    }
  }
}

// ---------------------------------------------------------------------------
extern "C" void kernel_launch(void* const* d_in, const int* in_sizes, int n_in,
                              void* d_out, int out_size, void* d_ws, size_t ws_size,
                              hipStream_t stream) {
  const float* x    = (const float*)d_in[0];  // [B,S,K] = [M,K]
  const float* w    = (const float*)d_in[1];  // [N,K]
  const float* bias = (const float*)d_in[2];  // [N]
  float* out = (float*)d_out;

  const int N = in_sizes[2];
  const int K = in_sizes[1] / N;
  const int M = (int)((long long)in_sizes[0] / K);

  ushort* xq = (ushort*)d_ws;                       // M*K bf16
  ushort* wq = xq + (size_t)M * K;                  // N*K bf16

  const long long nx = (long long)M * K;
  const long long nw = (long long)N * K;

  mxfp4_quant_kernel<<<dim3((unsigned)(nx / 1024)), dim3(256), 0, stream>>>(x, xq, nx);
  mxfp4_quant_kernel<<<dim3((unsigned)(nw / 1024)), dim3(256), 0, stream>>>(w, wq, nw);

  dim3 grid((M / BM) * (N / BN));
  mxfp_gemm_kernel<<<grid, dim3(NTHR), 0, stream>>>(xq, wq, bias, out, M, N, K);
}